// Round 10
// baseline (46.242 us; speedup 1.0000x reference)
//
#include <hip/hip_runtime.h>
#include <hip/hip_bf16.h>
#include <cmath>

#define BATCH  4
#define CDIM   64
#define CK     8
#define NSEQ   4096
#define NSPLIT 8
#define NCHUNK (NSEQ / NSPLIT)        // 512 n per attn block
#define NSUBS  (NCHUNK / 32)          // 16 PV subs per block
#define LOG2E  1.4426950408889634f

typedef __attribute__((ext_vector_type(8)))  short short8;
typedef __attribute__((ext_vector_type(16))) float f32x16;

__device__ inline unsigned short f2bf(float f) {
    union { float f; unsigned u; } v; v.f = f;
    unsigned r = v.u + 0x7fff + ((v.u >> 16) & 1);   // RNE
    return (unsigned short)(r >> 16);
}
__device__ inline float bf2f(unsigned short h) {
    union { unsigned u; float f; } v; v.u = ((unsigned)h) << 16;
    return v.f;
}

// -------------------------------------------------------------------------
// Kernel 1a (frozen): f = wq@x, g = wk@x (pre-scaled log2e).
// -------------------------------------------------------------------------
__global__ __launch_bounds__(256) void fg_kernel(
    const float* __restrict__ x,  const float* __restrict__ wq,
    const float* __restrict__ wk,
    unsigned short* __restrict__ f_pair, unsigned short* __restrict__ g_pair)
{
    __shared__ __align__(16) float s_wq[CDIM][12];
    __shared__ __align__(16) float s_wk[CDIM][12];

    const int t = threadIdx.x;
    #pragma unroll
    for (int u = 0; u < 2; ++u) {
        const int i = t + u * 256;
        const int k = i >> 6, c = i & 63;
        s_wq[c][k] = wq[i];
        s_wk[c][k] = wk[i];
    }
    __syncthreads();

    const int b  = blockIdx.x >> 7;
    const int n0 = (blockIdx.x & 127) * 32;
    const int nl = t >> 3;
    const int o  = t & 7;
    const int n  = n0 + nl;

    float fa[CK] = {0.f};
    float ga[CK] = {0.f};

    #pragma unroll
    for (int ci = 0; ci < 8; ++ci) {
        const int c   = 8 * o + ((ci + o) & 7);   // rotated: conflict-free
        const float xv = x[(b * CDIM + c) * NSEQ + n];

        const float4 q0 = *(const float4*)&s_wq[c][0];
        const float4 q1 = *(const float4*)&s_wq[c][4];
        fa[0] += q0.x * xv; fa[1] += q0.y * xv; fa[2] += q0.z * xv; fa[3] += q0.w * xv;
        fa[4] += q1.x * xv; fa[5] += q1.y * xv; fa[6] += q1.z * xv; fa[7] += q1.w * xv;

        const float4 k0  = *(const float4*)&s_wk[c][0];
        const float4 k1v = *(const float4*)&s_wk[c][4];
        ga[0] += k0.x * xv; ga[1] += k0.y * xv; ga[2] += k0.z * xv; ga[3] += k0.w * xv;
        ga[4] += k1v.x * xv; ga[5] += k1v.y * xv; ga[6] += k1v.z * xv; ga[7] += k1v.w * xv;
    }

    #pragma unroll
    for (int k = 0; k < CK; ++k) {
        fa[k] += __shfl_xor(fa[k], 1); fa[k] += __shfl_xor(fa[k], 2); fa[k] += __shfl_xor(fa[k], 4);
        ga[k] += __shfl_xor(ga[k], 1); ga[k] += __shfl_xor(ga[k], 2); ga[k] += __shfl_xor(ga[k], 4);
    }

    if (o == 0) {
        unsigned short buf[16];
        #pragma unroll
        for (int k = 0; k < CK; ++k) {
            buf[k]     = f2bf(fa[k]);
            buf[8 + k] = f2bf(fa[k] - bf2f(buf[k]));
        }
        uint4* dst = (uint4*)&f_pair[(size_t)(b * NSEQ + n) * 16];
        dst[0] = ((const uint4*)buf)[0];
        dst[1] = ((const uint4*)buf)[1];
    }
    if (o == 1) {
        unsigned short buf[16];
        #pragma unroll
        for (int k = 0; k < CK; ++k) {
            const float gs = ga[k] * LOG2E;
            buf[k]     = f2bf(gs);
            buf[8 + k] = f2bf(gs - bf2f(buf[k]));
        }
        uint4* dst = (uint4*)&g_pair[(size_t)(b * NSEQ + n) * 16];
        dst[0] = ((const uint4*)buf)[0];
        dst[1] = ((const uint4*)buf)[1];
    }
}

// -------------------------------------------------------------------------
// Kernel 1b: h = wv@x via MFMA, output in attn-fragment layout
// h_t[b][n/16][c][n%16] bf16. NEW: accs staged through LDS in the final
// layout, then written as fully-coalesced uint4 stores (4 KB contiguous
// per block) instead of 32x 2B scatter.
// -------------------------------------------------------------------------
__global__ __launch_bounds__(64) void h_kernel(
    const float* __restrict__ x, const float* __restrict__ wv,
    unsigned short* __restrict__ h_t)
{
    __shared__ __align__(16) unsigned short s_xt[32][72];   // [n][c] bf16 (reused)

    const int lane = threadIdx.x;
    const int hh   = lane >> 5;
    const int lm   = lane & 31;

    const int bid = blockIdx.x;            // 512 = b(4) x 128 n-tiles
    const int b   = bid >> 7;
    const int n0  = (bid & 127) * 32;

    union U4 { short8 v; unsigned short us[8]; };
    U4 Avh[2][4], Avl[2][4];
    #pragma unroll
    for (int mt2 = 0; mt2 < 2; ++mt2) {
        const int row = mt2 * 32 + lm;
        #pragma unroll
        for (int kc = 0; kc < 4; ++kc) {
            const int k0 = kc * 16 + hh * 8;
            const float4 w0 = *(const float4*)&wv[row * 64 + k0];
            const float4 w1 = *(const float4*)&wv[row * 64 + k0 + 4];
            const float wf[8] = {w0.x, w0.y, w0.z, w0.w, w1.x, w1.y, w1.z, w1.w};
            #pragma unroll
            for (int j = 0; j < 8; ++j) {
                const unsigned short hi = f2bf(wf[j]);
                Avh[mt2][kc].us[j] = hi;
                Avl[mt2][kc].us[j] = f2bf(wf[j] - bf2f(hi));
            }
        }
    }

    {
        const float* xs = &x[(size_t)(b * CDIM + lane) * NSEQ + n0];
        #pragma unroll
        for (int u = 0; u < 8; ++u) {
            const float4 v = *(const float4*)&xs[u * 4];
            s_xt[u*4 + 0][lane] = f2bf(v.x);
            s_xt[u*4 + 1][lane] = f2bf(v.y);
            s_xt[u*4 + 2][lane] = f2bf(v.z);
            s_xt[u*4 + 3][lane] = f2bf(v.w);
        }
    }
    __syncthreads();

    f32x16 acc0 = {}, acc1 = {};
    #pragma unroll
    for (int kc = 0; kc < 4; ++kc) {
        union U2x { short8 v; uint2 q[2]; } Bx;
        Bx.q[0] = *(const uint2*)&s_xt[lm][kc * 16 + hh * 8];
        Bx.q[1] = *(const uint2*)&s_xt[lm][kc * 16 + hh * 8 + 4];
        acc0 = __builtin_amdgcn_mfma_f32_32x32x16_bf16(Avh[0][kc].v, Bx.v, acc0, 0, 0, 0);
        acc0 = __builtin_amdgcn_mfma_f32_32x32x16_bf16(Avl[0][kc].v, Bx.v, acc0, 0, 0, 0);
        acc1 = __builtin_amdgcn_mfma_f32_32x32x16_bf16(Avh[1][kc].v, Bx.v, acc1, 0, 0, 0);
        acc1 = __builtin_amdgcn_mfma_f32_32x32x16_bf16(Avl[1][kc].v, Bx.v, acc1, 0, 0, 0);
    }

    // stage output tile in LDS in the FINAL h_t layout, then coalesced store
    __syncthreads();                                     // s_xt reads complete
    unsigned short* sh = &s_xt[0][0];                    // 2048 shorts used
    const int nb_lo = lm >> 4, ne = lm & 15;
    #pragma unroll
    for (int r = 0; r < 16; ++r) {
        const int c0 = (r & 3) + 8 * (r >> 2) + 4 * hh;
        sh[(nb_lo * CDIM + c0)      * 16 + ne] = f2bf(acc0[r]);
        sh[(nb_lo * CDIM + 32 + c0) * 16 + ne] = f2bf(acc1[r]);
    }
    __syncthreads();
    uint4* dst = (uint4*)&h_t[(size_t)(b * (NSEQ / 16) + (n0 >> 4)) * (CDIM * 16)];
    const uint4* srcl = (const uint4*)sh;
    #pragma unroll
    for (int u = 0; u < 4; ++u)
        dst[u * 64 + lane] = srcl[u * 64 + lane];
}

// -------------------------------------------------------------------------
// Kernel 2: barrier-free, LDS-free MFMA flash attention (round-9 structure).
// NEW: l computed via MFMA with A=ones (row-sum of the same bf16 P that PV
// consumes) -- deletes 16 v_add/sub + lsum chains + end shuffle.
// -------------------------------------------------------------------------
__global__ __launch_bounds__(64, 4) void attn_kernel(
    const unsigned short* __restrict__ f_pair,
    const unsigned short* __restrict__ g_pair,
    const unsigned short* __restrict__ h_t,
    unsigned short* __restrict__ o_part, float* __restrict__ l_part)
{
    const int lane = threadIdx.x;
    const int hh   = lane >> 5;
    const int lm   = lane & 31;

    const int bid = blockIdx.x;          // 4096 = s(8) * mt(128) * b(4)
    const int s   = bid & (NSPLIT - 1);
    const int mt  = (bid >> 3) & 127;
    const int b   = bid >> 10;

    const int m = mt * 32 + lm;

    union U4 { short8 v; uint4 q4; unsigned u[4]; unsigned short us[8]; };

    U4 Bgh, Bgl;
    {
        const uint4* gp = (const uint4*)&g_pair[(size_t)(b * NSEQ + m) * 16];
        Bgh.q4 = gp[0];
        Bgl.q4 = gp[1];
    }
    U4 Aones;
    #pragma unroll
    for (int j = 0; j < 8; ++j) Aones.us[j] = 0x3F80;    // bf16 1.0

    f32x16 acc0 = {}, acc1 = {}, accl = {};
    const f32x16 kZero = {};

    const unsigned short* fp = f_pair + (size_t)b * NSEQ * 16
                             + (size_t)lm * 16 + hh * 8;
    const unsigned short* ht = h_t + (size_t)(b * (NSEQ / 16) + s * (NCHUNK / 16)) * (CDIM * 16)
                             + hh * 8;

    auto loadAf = [&](int j) -> short8 {
        return *(const short8*)&fp[(size_t)(s * NCHUNK + j * 32) * 16];
    };
    auto loadH = [&](int j, uint4 (&ha)[2], uint4 (&hb2)[2]) {
        #pragma unroll
        for (int ks = 0; ks < 2; ++ks) {
            ha[ks]  = *(const uint4*)&ht[(size_t)((j * 2 + ks) * CDIM + lm) * 16];
            hb2[ks] = *(const uint4*)&ht[(size_t)((j * 2 + ks) * CDIM + 32 + lm) * 16];
        }
    };

    short8 af[2];
    uint4  hA[2][2], hB[2][2];

    af[0] = loadAf(0); loadH(0, hA[0], hB[0]);
    af[1] = loadAf(1); loadH(1, hA[1], hB[1]);

    #pragma unroll
    for (int j = 0; j < NSUBS; ++j) {
        const int cur = j & 1;

        f32x16 sc = __builtin_amdgcn_mfma_f32_32x32x16_bf16(af[cur], Bgh.v, kZero, 0, 0, 0);
        sc = __builtin_amdgcn_mfma_f32_32x32x16_bf16(af[cur], Bgl.v, sc, 0, 0, 0);

        if (j + 2 < NSUBS) af[cur] = loadAf(j + 2);

        unsigned a[8];
        #pragma unroll
        for (int p = 0; p < 8; ++p) {
            const float e0 = __builtin_amdgcn_exp2f(sc[2*p]);
            const float e1 = __builtin_amdgcn_exp2f(sc[2*p+1]);
            __hip_bfloat162 h2 = __float22bfloat162_rn(make_float2(e0, e1));
            a[p] = *(unsigned*)&h2;
        }
        const auto s02 = __builtin_amdgcn_permlane32_swap(a[0], a[2], false, false);
        const auto s13 = __builtin_amdgcn_permlane32_swap(a[1], a[3], false, false);
        const auto s46 = __builtin_amdgcn_permlane32_swap(a[4], a[6], false, false);
        const auto s57 = __builtin_amdgcn_permlane32_swap(a[5], a[7], false, false);

        U4 P0, P1;
        P0.u[0] = s02[0]; P0.u[1] = s13[0]; P0.u[2] = s02[1]; P0.u[3] = s13[1];
        P1.u[0] = s46[0]; P1.u[1] = s57[0]; P1.u[2] = s46[1]; P1.u[3] = s57[1];

        union U2x { short8 v; uint4 q; } Ax;
        __builtin_amdgcn_s_setprio(1);
        Ax.q = hA[cur][0];
        acc0 = __builtin_amdgcn_mfma_f32_32x32x16_bf16(Ax.v, P0.v, acc0, 0, 0, 0);
        Ax.q = hB[cur][0];
        acc1 = __builtin_amdgcn_mfma_f32_32x32x16_bf16(Ax.v, P0.v, acc1, 0, 0, 0);
        accl = __builtin_amdgcn_mfma_f32_32x32x16_bf16(Aones.v, P0.v, accl, 0, 0, 0);
        Ax.q = hA[cur][1];
        acc0 = __builtin_amdgcn_mfma_f32_32x32x16_bf16(Ax.v, P1.v, acc0, 0, 0, 0);
        Ax.q = hB[cur][1];
        acc1 = __builtin_amdgcn_mfma_f32_32x32x16_bf16(Ax.v, P1.v, acc1, 0, 0, 0);
        accl = __builtin_amdgcn_mfma_f32_32x32x16_bf16(Aones.v, P1.v, accl, 0, 0, 0);
        __builtin_amdgcn_s_setprio(0);

        if (j + 2 < NSUBS) loadH(j + 2, hA[cur], hB[cur]);
    }

    // accl[0] = sum_n P[n][m] -- complete per lane (P0/P1 span the full sub)
    if (hh == 0) l_part[(s * BATCH + b) * NSEQ + m] = accl[0];

    unsigned short* ob = o_part + (size_t)(s * BATCH + b) * CDIM * NSEQ;
    #pragma unroll
    for (int r = 0; r < 16; ++r) {
        const int c0 = (r & 3) + 8 * (r >> 2) + 4 * hh;
        ob[(size_t)c0 * NSEQ + m]        = f2bf(acc0[r]);
        ob[(size_t)(32 + c0) * NSEQ + m] = f2bf(acc1[r]);
    }
}

// -------------------------------------------------------------------------
// Kernel 3 (frozen): out = gamma * (sum_s o_part) / (sum_s l_part) + x
// -------------------------------------------------------------------------
__global__ __launch_bounds__(256) void final_kernel(
    const float* __restrict__ x, const unsigned short* __restrict__ o_part,
    const float* __restrict__ l_part, const float* __restrict__ gamma,
    float* __restrict__ out)
{
    const size_t i = (size_t)(blockIdx.x * 256 + threadIdx.x) * 8;
    const int m = (int)(i & (NSEQ - 1));
    const int b = (int)(i >> 18);

    float o[8] = {0.f,0.f,0.f,0.f,0.f,0.f,0.f,0.f};
    float l[8] = {0.f,0.f,0.f,0.f,0.f,0.f,0.f,0.f};
    #pragma unroll
    for (int s = 0; s < NSPLIT; ++s) {
        const uint4 ov = *(const uint4*)&o_part[(size_t)s * (BATCH * CDIM * NSEQ) + i];
        const unsigned short* os = (const unsigned short*)&ov;
        #pragma unroll
        for (int j = 0; j < 8; ++j) o[j] += bf2f(os[j]);
        const float* lp = &l_part[s * (BATCH * NSEQ) + b * NSEQ + m];
        const float4 l0 = *(const float4*)&lp[0];
        const float4 l1 = *(const float4*)&lp[4];
        l[0] += l0.x; l[1] += l0.y; l[2] += l0.z; l[3] += l0.w;
        l[4] += l1.x; l[5] += l1.y; l[6] += l1.z; l[7] += l1.w;
    }
    const float g = gamma[0];
    const float4 x0 = *(const float4*)&x[i];
    const float4 x1 = *(const float4*)&x[i + 4];
    float4 o0, o1;
    o0.x = g * o[0] / l[0] + x0.x;  o0.y = g * o[1] / l[1] + x0.y;
    o0.z = g * o[2] / l[2] + x0.z;  o0.w = g * o[3] / l[3] + x0.w;
    o1.x = g * o[4] / l[4] + x1.x;  o1.y = g * o[5] / l[5] + x1.y;
    o1.z = g * o[6] / l[6] + x1.z;  o1.w = g * o[7] / l[7] + x1.w;
    *(float4*)&out[i]     = o0;
    *(float4*)&out[i + 4] = o1;
}

extern "C" void kernel_launch(void* const* d_in, const int* in_sizes, int n_in,
                              void* d_out, int out_size, void* d_ws, size_t ws_size,
                              hipStream_t stream) {
    const float* x     = (const float*)d_in[0];
    const float* wq    = (const float*)d_in[1];
    const float* wk    = (const float*)d_in[2];
    const float* wv    = (const float*)d_in[3];
    const float* gamma = (const float*)d_in[4];
    float* out = (float*)d_out;

    char* wsb = (char*)d_ws;
    unsigned short* f_pair = (unsigned short*)wsb;                         // 512 KB
    unsigned short* g_pair = f_pair + (size_t)BATCH * NSEQ * 16;           // 512 KB
    unsigned short* h_t    = g_pair + (size_t)BATCH * NSEQ * 16;           // 2 MB
    unsigned short* o_part = (unsigned short*)(wsb + 3u * 1024 * 1024);    // 16 MB (bf16)
    float* l_part = (float*)(wsb + 19u * 1024 * 1024);                     // 512 KB

    hipLaunchKernelGGL(fg_kernel, dim3(512), dim3(256), 0, stream,
                       x, wq, wk, f_pair, g_pair);
    hipLaunchKernelGGL(h_kernel, dim3(512), dim3(64), 0, stream,
                       x, wv, h_t);
    hipLaunchKernelGGL(attn_kernel, dim3(BATCH * 128 * NSPLIT), dim3(64), 0, stream,
                       f_pair, g_pair, h_t, o_part, l_part);
    hipLaunchKernelGGL(final_kernel, dim3((BATCH * CDIM * NSEQ) / (256 * 8)), dim3(256), 0, stream,
                       x, o_part, l_part, gamma, out);
}

// Round 12
// 40.504 us; speedup vs baseline: 1.1417x; 1.1417x over previous
//
#include <hip/hip_runtime.h>
#include <hip/hip_bf16.h>
#include <cmath>

#define BATCH  4
#define CDIM   64
#define CK     8
#define NSEQ   4096
#define NSPLIT 8
#define NCHUNK (NSEQ / NSPLIT)        // 512 n per wave
#define NSUBS  (NCHUNK / 32)          // 16 PV subs per wave
#define LOG2E  1.4426950408889634f

typedef __attribute__((ext_vector_type(8)))  short short8;
typedef __attribute__((ext_vector_type(16))) float f32x16;

__device__ inline unsigned short f2bf(float f) {
    union { float f; unsigned u; } v; v.f = f;
    unsigned r = v.u + 0x7fff + ((v.u >> 16) & 1);   // RNE
    return (unsigned short)(r >> 16);
}
__device__ inline float bf2f(unsigned short h) {
    union { unsigned u; float f; } v; v.u = ((unsigned)h) << 16;
    return v.f;
}

// -------------------------------------------------------------------------
// Kernel 1 (fused prep): blocks [0,512) compute f = wq@x, g = wk@x
// (round-10 fg path, verified); blocks [512,640) compute h = wv@x via MFMA
// (round-10 h path, 4 independent waves per block). One launch, overlapped.
// -------------------------------------------------------------------------
__global__ __launch_bounds__(256) void prep_kernel(
    const float* __restrict__ x,  const float* __restrict__ wq,
    const float* __restrict__ wk, const float* __restrict__ wv,
    unsigned short* __restrict__ f_pair, unsigned short* __restrict__ g_pair,
    unsigned short* __restrict__ h_t)
{
    __shared__ __align__(16) float s_wq[CDIM][12];
    __shared__ __align__(16) float s_wk[CDIM][12];
    __shared__ __align__(16) unsigned short s_xt[4][32][72];

    const int t = threadIdx.x;

    if (blockIdx.x < 512) {
        // ---------------- fg path (frozen round-10 code) ----------------
        #pragma unroll
        for (int u = 0; u < 2; ++u) {
            const int i = t + u * 256;
            const int k = i >> 6, c = i & 63;
            s_wq[c][k] = wq[i];
            s_wk[c][k] = wk[i];
        }
        __syncthreads();

        const int b  = blockIdx.x >> 7;
        const int n0 = (blockIdx.x & 127) * 32;
        const int nl = t >> 3;
        const int o  = t & 7;
        const int n  = n0 + nl;

        float fa[CK] = {0.f};
        float ga[CK] = {0.f};

        #pragma unroll
        for (int ci = 0; ci < 8; ++ci) {
            const int c   = 8 * o + ((ci + o) & 7);   // rotated: conflict-free
            const float xv = x[(b * CDIM + c) * NSEQ + n];

            const float4 q0 = *(const float4*)&s_wq[c][0];
            const float4 q1 = *(const float4*)&s_wq[c][4];
            fa[0] += q0.x * xv; fa[1] += q0.y * xv; fa[2] += q0.z * xv; fa[3] += q0.w * xv;
            fa[4] += q1.x * xv; fa[5] += q1.y * xv; fa[6] += q1.z * xv; fa[7] += q1.w * xv;

            const float4 k0  = *(const float4*)&s_wk[c][0];
            const float4 k1v = *(const float4*)&s_wk[c][4];
            ga[0] += k0.x * xv; ga[1] += k0.y * xv; ga[2] += k0.z * xv; ga[3] += k0.w * xv;
            ga[4] += k1v.x * xv; ga[5] += k1v.y * xv; ga[6] += k1v.z * xv; ga[7] += k1v.w * xv;
        }

        #pragma unroll
        for (int k = 0; k < CK; ++k) {
            fa[k] += __shfl_xor(fa[k], 1); fa[k] += __shfl_xor(fa[k], 2); fa[k] += __shfl_xor(fa[k], 4);
            ga[k] += __shfl_xor(ga[k], 1); ga[k] += __shfl_xor(ga[k], 2); ga[k] += __shfl_xor(ga[k], 4);
        }

        if (o == 0) {
            unsigned short buf[16];
            #pragma unroll
            for (int k = 0; k < CK; ++k) {
                buf[k]     = f2bf(fa[k]);
                buf[8 + k] = f2bf(fa[k] - bf2f(buf[k]));
            }
            uint4* dst = (uint4*)&f_pair[(size_t)(b * NSEQ + n) * 16];
            dst[0] = ((const uint4*)buf)[0];
            dst[1] = ((const uint4*)buf)[1];
        }
        if (o == 1) {
            unsigned short buf[16];
            #pragma unroll
            for (int k = 0; k < CK; ++k) {
                const float gs = ga[k] * LOG2E;
                buf[k]     = f2bf(gs);
                buf[8 + k] = f2bf(gs - bf2f(buf[k]));
            }
            uint4* dst = (uint4*)&g_pair[(size_t)(b * NSEQ + n) * 16];
            dst[0] = ((const uint4*)buf)[0];
            dst[1] = ((const uint4*)buf)[1];
        }
    } else {
        // ---------------- h path (frozen round-10 code, 4 waves) ----------------
        const int w    = t >> 6;
        const int lane = t & 63;
        const int hh   = lane >> 5;
        const int lm   = lane & 31;

        const int tile = (blockIdx.x - 512) * 4 + w;   // [0,512)
        const int b    = tile >> 7;
        const int n0   = (tile & 127) * 32;

        union U4 { short8 v; unsigned short us[8]; };
        U4 Avh[2][4], Avl[2][4];
        #pragma unroll
        for (int mt2 = 0; mt2 < 2; ++mt2) {
            const int row = mt2 * 32 + lm;
            #pragma unroll
            for (int kc = 0; kc < 4; ++kc) {
                const int k0 = kc * 16 + hh * 8;
                const float4 w0 = *(const float4*)&wv[row * 64 + k0];
                const float4 w1 = *(const float4*)&wv[row * 64 + k0 + 4];
                const float wf[8] = {w0.x, w0.y, w0.z, w0.w, w1.x, w1.y, w1.z, w1.w};
                #pragma unroll
                for (int j = 0; j < 8; ++j) {
                    const unsigned short hi = f2bf(wf[j]);
                    Avh[mt2][kc].us[j] = hi;
                    Avl[mt2][kc].us[j] = f2bf(wf[j] - bf2f(hi));
                }
            }
        }

        {
            const float* xs = &x[(size_t)(b * CDIM + lane) * NSEQ + n0];
            #pragma unroll
            for (int u = 0; u < 8; ++u) {
                const float4 v = *(const float4*)&xs[u * 4];
                s_xt[w][u*4 + 0][lane] = f2bf(v.x);
                s_xt[w][u*4 + 1][lane] = f2bf(v.y);
                s_xt[w][u*4 + 2][lane] = f2bf(v.z);
                s_xt[w][u*4 + 3][lane] = f2bf(v.w);
            }
        }
        __syncthreads();

        f32x16 acc0 = {}, acc1 = {};
        #pragma unroll
        for (int kc = 0; kc < 4; ++kc) {
            union U2x { short8 v; uint2 q[2]; } Bx;
            Bx.q[0] = *(const uint2*)&s_xt[w][lm][kc * 16 + hh * 8];
            Bx.q[1] = *(const uint2*)&s_xt[w][lm][kc * 16 + hh * 8 + 4];
            acc0 = __builtin_amdgcn_mfma_f32_32x32x16_bf16(Avh[0][kc].v, Bx.v, acc0, 0, 0, 0);
            acc0 = __builtin_amdgcn_mfma_f32_32x32x16_bf16(Avl[0][kc].v, Bx.v, acc0, 0, 0, 0);
            acc1 = __builtin_amdgcn_mfma_f32_32x32x16_bf16(Avh[1][kc].v, Bx.v, acc1, 0, 0, 0);
            acc1 = __builtin_amdgcn_mfma_f32_32x32x16_bf16(Avl[1][kc].v, Bx.v, acc1, 0, 0, 0);
        }

        __syncthreads();
        unsigned short* sh = &s_xt[w][0][0];
        const int nb_lo = lm >> 4, ne = lm & 15;
        #pragma unroll
        for (int r = 0; r < 16; ++r) {
            const int c0 = (r & 3) + 8 * (r >> 2) + 4 * hh;
            sh[(nb_lo * CDIM + c0)      * 16 + ne] = f2bf(acc0[r]);
            sh[(nb_lo * CDIM + 32 + c0) * 16 + ne] = f2bf(acc1[r]);
        }
        __syncthreads();
        uint4* dst = (uint4*)&h_t[(size_t)(b * (NSEQ / 16) + (n0 >> 4)) * (CDIM * 16)];
        const uint4* srcl = (const uint4*)sh;
        #pragma unroll
        for (int u = 0; u < 4; ++u)
            dst[u * 64 + lane] = srcl[u * 64 + lane];
    }
}

// -------------------------------------------------------------------------
// Kernel 2: fused flash attention + epilogue. 512 blocks x 512 threads.
// Wave s handles n-split s of the SAME 32 m-columns (round-10 inner loop,
// barrier-free per wave, header bf16 pack). End: 8-phase LDS fp32 reduction
// of (o, l) across waves, then out = gamma*o/l + x written directly.
// -------------------------------------------------------------------------
__global__ __launch_bounds__(512, 4) void attn_kernel(
    const unsigned short* __restrict__ f_pair,
    const unsigned short* __restrict__ g_pair,
    const unsigned short* __restrict__ h_t,
    const float* __restrict__ x, const float* __restrict__ gamma,
    float* __restrict__ out)
{
    __shared__ __align__(16) float s_o[CDIM][36];   // padded: rows 144B (16B-aligned)
    __shared__ __align__(16) float s_l[32];

    const int t    = threadIdx.x;
    const int w    = t >> 6;             // wave = n-split s
    const int lane = t & 63;
    const int hh   = lane >> 5;
    const int lm   = lane & 31;

    const int bid = blockIdx.x;          // 512 = b(4) * mt(128)
    const int mt  = bid & 127;
    const int b   = bid >> 7;
    const int s   = w;

    const int m = mt * 32 + lm;

    union U4 { short8 v; uint4 q4; unsigned u[4]; unsigned short us[8]; };

    U4 Bgh, Bgl;
    {
        const uint4* gp = (const uint4*)&g_pair[(size_t)(b * NSEQ + m) * 16];
        Bgh.q4 = gp[0];
        Bgl.q4 = gp[1];
    }
    U4 Aones;
    #pragma unroll
    for (int j = 0; j < 8; ++j) Aones.us[j] = 0x3F80;    // bf16 1.0

    f32x16 acc0 = {}, acc1 = {}, accl = {};
    const f32x16 kZero = {};

    const unsigned short* fp = f_pair + (size_t)b * NSEQ * 16
                             + (size_t)lm * 16 + hh * 8;
    const unsigned short* ht = h_t + (size_t)(b * (NSEQ / 16) + s * (NCHUNK / 16)) * (CDIM * 16)
                             + hh * 8;

    auto loadAf = [&](int j) -> short8 {
        return *(const short8*)&fp[(size_t)(s * NCHUNK + j * 32) * 16];
    };
    auto loadH = [&](int j, uint4 (&ha)[2], uint4 (&hb2)[2]) {
        #pragma unroll
        for (int ks = 0; ks < 2; ++ks) {
            ha[ks]  = *(const uint4*)&ht[(size_t)((j * 2 + ks) * CDIM + lm) * 16];
            hb2[ks] = *(const uint4*)&ht[(size_t)((j * 2 + ks) * CDIM + 32 + lm) * 16];
        }
    };

    short8 af[2];
    uint4  hA[2][2], hB[2][2];

    af[0] = loadAf(0); loadH(0, hA[0], hB[0]);
    af[1] = loadAf(1); loadH(1, hA[1], hB[1]);

    #pragma unroll
    for (int j = 0; j < NSUBS; ++j) {
        const int cur = j & 1;

        f32x16 sc = __builtin_amdgcn_mfma_f32_32x32x16_bf16(af[cur], Bgh.v, kZero, 0, 0, 0);
        sc = __builtin_amdgcn_mfma_f32_32x32x16_bf16(af[cur], Bgl.v, sc, 0, 0, 0);

        if (j + 2 < NSUBS) af[cur] = loadAf(j + 2);

        unsigned a[8];
        #pragma unroll
        for (int p = 0; p < 8; ++p) {
            const float e0 = __builtin_amdgcn_exp2f(sc[2*p]);
            const float e1 = __builtin_amdgcn_exp2f(sc[2*p+1]);
            __hip_bfloat162 h2 = __float22bfloat162_rn(make_float2(e0, e1));
            a[p] = *(unsigned*)&h2;
        }
        const auto s02 = __builtin_amdgcn_permlane32_swap(a[0], a[2], false, false);
        const auto s13 = __builtin_amdgcn_permlane32_swap(a[1], a[3], false, false);
        const auto s46 = __builtin_amdgcn_permlane32_swap(a[4], a[6], false, false);
        const auto s57 = __builtin_amdgcn_permlane32_swap(a[5], a[7], false, false);

        U4 P0, P1;
        P0.u[0] = s02[0]; P0.u[1] = s13[0]; P0.u[2] = s02[1]; P0.u[3] = s13[1];
        P1.u[0] = s46[0]; P1.u[1] = s57[0]; P1.u[2] = s46[1]; P1.u[3] = s57[1];

        union U2x { short8 v; uint4 q; } Ax;
        __builtin_amdgcn_s_setprio(1);
        Ax.q = hA[cur][0];
        acc0 = __builtin_amdgcn_mfma_f32_32x32x16_bf16(Ax.v, P0.v, acc0, 0, 0, 0);
        Ax.q = hB[cur][0];
        acc1 = __builtin_amdgcn_mfma_f32_32x32x16_bf16(Ax.v, P0.v, acc1, 0, 0, 0);
        accl = __builtin_amdgcn_mfma_f32_32x32x16_bf16(Aones.v, P0.v, accl, 0, 0, 0);
        Ax.q = hA[cur][1];
        acc0 = __builtin_amdgcn_mfma_f32_32x32x16_bf16(Ax.v, P1.v, acc0, 0, 0, 0);
        Ax.q = hB[cur][1];
        acc1 = __builtin_amdgcn_mfma_f32_32x32x16_bf16(Ax.v, P1.v, acc1, 0, 0, 0);
        accl = __builtin_amdgcn_mfma_f32_32x32x16_bf16(Aones.v, P1.v, accl, 0, 0, 0);
        __builtin_amdgcn_s_setprio(0);

        if (j + 2 < NSUBS) loadH(j + 2, hA[cur], hB[cur]);
    }

    // ---- 8-phase in-block fp32 reduction of (o, l) across the 8 waves ----
    #pragma unroll
    for (int ws = 0; ws < NSPLIT; ++ws) {
        if (w == ws) {
            if (ws == 0) {
                #pragma unroll
                for (int r = 0; r < 16; ++r) {
                    const int c0 = (r & 3) + 8 * (r >> 2) + 4 * hh;
                    s_o[c0][lm]      = acc0[r];
                    s_o[32 + c0][lm] = acc1[r];
                }
                if (hh == 0) s_l[lm] = accl[0];
            } else {
                #pragma unroll
                for (int r = 0; r < 16; ++r) {
                    const int c0 = (r & 3) + 8 * (r >> 2) + 4 * hh;
                    s_o[c0][lm]      += acc0[r];
                    s_o[32 + c0][lm] += acc1[r];
                }
                if (hh == 0) s_l[lm] += accl[0];
            }
        }
        __syncthreads();
    }

    // ---- epilogue: out = gamma * o / l + x (coalesced float4) ----
    {
        const float g  = gamma[0];
        const int   c  = t >> 3;            // 0..63
        const int   mg = (t & 7) * 4;       // 0,4,..,28
        const float4 ov = *(const float4*)&s_o[c][mg];
        const float4 lv = *(const float4*)&s_l[mg];
        const size_t idx = (size_t)(b * CDIM + c) * NSEQ + mt * 32 + mg;
        const float4 xv = *(const float4*)&x[idx];
        float4 r;
        r.x = g * ov.x / lv.x + xv.x;
        r.y = g * ov.y / lv.y + xv.y;
        r.z = g * ov.z / lv.z + xv.z;
        r.w = g * ov.w / lv.w + xv.w;
        *(float4*)&out[idx] = r;
    }
}

extern "C" void kernel_launch(void* const* d_in, const int* in_sizes, int n_in,
                              void* d_out, int out_size, void* d_ws, size_t ws_size,
                              hipStream_t stream) {
    const float* x     = (const float*)d_in[0];
    const float* wq    = (const float*)d_in[1];
    const float* wk    = (const float*)d_in[2];
    const float* wv    = (const float*)d_in[3];
    const float* gamma = (const float*)d_in[4];
    float* out = (float*)d_out;

    char* wsb = (char*)d_ws;
    unsigned short* f_pair = (unsigned short*)wsb;                         // 512 KB
    unsigned short* g_pair = f_pair + (size_t)BATCH * NSEQ * 16;           // 512 KB
    unsigned short* h_t    = g_pair + (size_t)BATCH * NSEQ * 16;           // 2 MB

    hipLaunchKernelGGL(prep_kernel, dim3(640), dim3(256), 0, stream,
                       x, wq, wk, wv, f_pair, g_pair, h_t);
    hipLaunchKernelGGL(attn_kernel, dim3(BATCH * 128), dim3(512), 0, stream,
                       f_pair, g_pair, h_t, x, gamma, out);
}

// Round 13
// 36.047 us; speedup vs baseline: 1.2828x; 1.1236x over previous
//
#include <hip/hip_runtime.h>
#include <hip/hip_bf16.h>
#include <cmath>

#define BATCH  4
#define CDIM   64
#define CK     8
#define NSEQ   4096
#define NSPLIT 8
#define NCHUNK (NSEQ / NSPLIT)        // 512 n per wave
#define NSUBS  (NCHUNK / 32)          // 16 PV subs per wave
#define LOG2E  1.4426950408889634f

typedef __attribute__((ext_vector_type(8)))  short short8;
typedef __attribute__((ext_vector_type(16))) float f32x16;

__device__ inline unsigned short f2bf(float f) {
    union { float f; unsigned u; } v; v.f = f;
    unsigned r = v.u + 0x7fff + ((v.u >> 16) & 1);   // RNE
    return (unsigned short)(r >> 16);
}
__device__ inline float bf2f(unsigned short h) {
    union { unsigned u; float f; } v; v.u = ((unsigned)h) << 16;
    return v.f;
}

// -------------------------------------------------------------------------
// Kernel 1 (frozen from round 12): fused prep. Blocks [0,512): f,g;
// blocks [512,640): h via MFMA into fragment layout h_t.
// -------------------------------------------------------------------------
__global__ __launch_bounds__(256) void prep_kernel(
    const float* __restrict__ x,  const float* __restrict__ wq,
    const float* __restrict__ wk, const float* __restrict__ wv,
    unsigned short* __restrict__ f_pair, unsigned short* __restrict__ g_pair,
    unsigned short* __restrict__ h_t)
{
    __shared__ __align__(16) float s_wq[CDIM][12];
    __shared__ __align__(16) float s_wk[CDIM][12];
    __shared__ __align__(16) unsigned short s_xt[4][32][72];

    const int t = threadIdx.x;

    if (blockIdx.x < 512) {
        #pragma unroll
        for (int u = 0; u < 2; ++u) {
            const int i = t + u * 256;
            const int k = i >> 6, c = i & 63;
            s_wq[c][k] = wq[i];
            s_wk[c][k] = wk[i];
        }
        __syncthreads();

        const int b  = blockIdx.x >> 7;
        const int n0 = (blockIdx.x & 127) * 32;
        const int nl = t >> 3;
        const int o  = t & 7;
        const int n  = n0 + nl;

        float fa[CK] = {0.f};
        float ga[CK] = {0.f};

        #pragma unroll
        for (int ci = 0; ci < 8; ++ci) {
            const int c   = 8 * o + ((ci + o) & 7);   // rotated: conflict-free
            const float xv = x[(b * CDIM + c) * NSEQ + n];

            const float4 q0 = *(const float4*)&s_wq[c][0];
            const float4 q1 = *(const float4*)&s_wq[c][4];
            fa[0] += q0.x * xv; fa[1] += q0.y * xv; fa[2] += q0.z * xv; fa[3] += q0.w * xv;
            fa[4] += q1.x * xv; fa[5] += q1.y * xv; fa[6] += q1.z * xv; fa[7] += q1.w * xv;

            const float4 k0  = *(const float4*)&s_wk[c][0];
            const float4 k1v = *(const float4*)&s_wk[c][4];
            ga[0] += k0.x * xv; ga[1] += k0.y * xv; ga[2] += k0.z * xv; ga[3] += k0.w * xv;
            ga[4] += k1v.x * xv; ga[5] += k1v.y * xv; ga[6] += k1v.z * xv; ga[7] += k1v.w * xv;
        }

        #pragma unroll
        for (int k = 0; k < CK; ++k) {
            fa[k] += __shfl_xor(fa[k], 1); fa[k] += __shfl_xor(fa[k], 2); fa[k] += __shfl_xor(fa[k], 4);
            ga[k] += __shfl_xor(ga[k], 1); ga[k] += __shfl_xor(ga[k], 2); ga[k] += __shfl_xor(ga[k], 4);
        }

        if (o == 0) {
            unsigned short buf[16];
            #pragma unroll
            for (int k = 0; k < CK; ++k) {
                buf[k]     = f2bf(fa[k]);
                buf[8 + k] = f2bf(fa[k] - bf2f(buf[k]));
            }
            uint4* dst = (uint4*)&f_pair[(size_t)(b * NSEQ + n) * 16];
            dst[0] = ((const uint4*)buf)[0];
            dst[1] = ((const uint4*)buf)[1];
        }
        if (o == 1) {
            unsigned short buf[16];
            #pragma unroll
            for (int k = 0; k < CK; ++k) {
                const float gs = ga[k] * LOG2E;
                buf[k]     = f2bf(gs);
                buf[8 + k] = f2bf(gs - bf2f(buf[k]));
            }
            uint4* dst = (uint4*)&g_pair[(size_t)(b * NSEQ + n) * 16];
            dst[0] = ((const uint4*)buf)[0];
            dst[1] = ((const uint4*)buf)[1];
        }
    } else {
        const int w    = t >> 6;
        const int lane = t & 63;
        const int hh   = lane >> 5;
        const int lm   = lane & 31;

        const int tile = (blockIdx.x - 512) * 4 + w;   // [0,512)
        const int b    = tile >> 7;
        const int n0   = (tile & 127) * 32;

        union U4 { short8 v; unsigned short us[8]; };
        U4 Avh[2][4], Avl[2][4];
        #pragma unroll
        for (int mt2 = 0; mt2 < 2; ++mt2) {
            const int row = mt2 * 32 + lm;
            #pragma unroll
            for (int kc = 0; kc < 4; ++kc) {
                const int k0 = kc * 16 + hh * 8;
                const float4 w0 = *(const float4*)&wv[row * 64 + k0];
                const float4 w1 = *(const float4*)&wv[row * 64 + k0 + 4];
                const float wf[8] = {w0.x, w0.y, w0.z, w0.w, w1.x, w1.y, w1.z, w1.w};
                #pragma unroll
                for (int j = 0; j < 8; ++j) {
                    const unsigned short hi = f2bf(wf[j]);
                    Avh[mt2][kc].us[j] = hi;
                    Avl[mt2][kc].us[j] = f2bf(wf[j] - bf2f(hi));
                }
            }
        }

        {
            const float* xs = &x[(size_t)(b * CDIM + lane) * NSEQ + n0];
            #pragma unroll
            for (int u = 0; u < 8; ++u) {
                const float4 v = *(const float4*)&xs[u * 4];
                s_xt[w][u*4 + 0][lane] = f2bf(v.x);
                s_xt[w][u*4 + 1][lane] = f2bf(v.y);
                s_xt[w][u*4 + 2][lane] = f2bf(v.z);
                s_xt[w][u*4 + 3][lane] = f2bf(v.w);
            }
        }
        __syncthreads();

        f32x16 acc0 = {}, acc1 = {};
        #pragma unroll
        for (int kc = 0; kc < 4; ++kc) {
            union U2x { short8 v; uint2 q[2]; } Bx;
            Bx.q[0] = *(const uint2*)&s_xt[w][lm][kc * 16 + hh * 8];
            Bx.q[1] = *(const uint2*)&s_xt[w][lm][kc * 16 + hh * 8 + 4];
            acc0 = __builtin_amdgcn_mfma_f32_32x32x16_bf16(Avh[0][kc].v, Bx.v, acc0, 0, 0, 0);
            acc0 = __builtin_amdgcn_mfma_f32_32x32x16_bf16(Avl[0][kc].v, Bx.v, acc0, 0, 0, 0);
            acc1 = __builtin_amdgcn_mfma_f32_32x32x16_bf16(Avh[1][kc].v, Bx.v, acc1, 0, 0, 0);
            acc1 = __builtin_amdgcn_mfma_f32_32x32x16_bf16(Avl[1][kc].v, Bx.v, acc1, 0, 0, 0);
        }

        __syncthreads();
        unsigned short* sh = &s_xt[w][0][0];
        const int nb_lo = lm >> 4, ne = lm & 15;
        #pragma unroll
        for (int r = 0; r < 16; ++r) {
            const int c0 = (r & 3) + 8 * (r >> 2) + 4 * hh;
            sh[(nb_lo * CDIM + c0)      * 16 + ne] = f2bf(acc0[r]);
            sh[(nb_lo * CDIM + 32 + c0) * 16 + ne] = f2bf(acc1[r]);
        }
        __syncthreads();
        uint4* dst = (uint4*)&h_t[(size_t)(b * (NSEQ / 16) + (n0 >> 4)) * (CDIM * 16)];
        const uint4* srcl = (const uint4*)sh;
        #pragma unroll
        for (int u = 0; u < 4; ++u)
            dst[u * 64 + lane] = srcl[u * 64 + lane];
    }
}

// -------------------------------------------------------------------------
// Kernel 2: fused flash attention + epilogue (round-12 structure).
// SPILL DIET: no accl/Aones (l via two fp32 add chains), no persistent
// kZero (inline {}), peak live VGPR ~107 < 128 cap at (512,4) -> no scratch.
// -------------------------------------------------------------------------
__global__ __launch_bounds__(512, 4) void attn_kernel(
    const unsigned short* __restrict__ f_pair,
    const unsigned short* __restrict__ g_pair,
    const unsigned short* __restrict__ h_t,
    const float* __restrict__ x, const float* __restrict__ gamma,
    float* __restrict__ out)
{
    __shared__ __align__(16) float s_o[CDIM][36];   // padded rows (144B)
    __shared__ __align__(16) float s_l[32];

    const int t    = threadIdx.x;
    const int w    = t >> 6;             // wave = n-split s
    const int lane = t & 63;
    const int hh   = lane >> 5;
    const int lm   = lane & 31;

    const int bid = blockIdx.x;          // 512 = b(4) * mt(128)
    const int mt  = bid & 127;
    const int b   = bid >> 7;
    const int s   = w;

    const int m = mt * 32 + lm;

    union U4 { short8 v; uint4 q4; unsigned u[4]; unsigned short us[8]; };

    U4 Bgh, Bgl;
    {
        const uint4* gp = (const uint4*)&g_pair[(size_t)(b * NSEQ + m) * 16];
        Bgh.q4 = gp[0];
        Bgl.q4 = gp[1];
    }

    f32x16 acc0 = {}, acc1 = {};
    float lsA = 0.f, lsB = 0.f;

    const unsigned short* fp = f_pair + (size_t)b * NSEQ * 16
                             + (size_t)lm * 16 + hh * 8;
    const unsigned short* ht = h_t + (size_t)(b * (NSEQ / 16) + s * (NCHUNK / 16)) * (CDIM * 16)
                             + hh * 8;

    auto loadAf = [&](int j) -> short8 {
        return *(const short8*)&fp[(size_t)(s * NCHUNK + j * 32) * 16];
    };
    auto loadH = [&](int j, uint4 (&ha)[2], uint4 (&hb2)[2]) {
        #pragma unroll
        for (int ks = 0; ks < 2; ++ks) {
            ha[ks]  = *(const uint4*)&ht[(size_t)((j * 2 + ks) * CDIM + lm) * 16];
            hb2[ks] = *(const uint4*)&ht[(size_t)((j * 2 + ks) * CDIM + 32 + lm) * 16];
        }
    };

    short8 af[2];
    uint4  hA[2][2], hB[2][2];

    af[0] = loadAf(0); loadH(0, hA[0], hB[0]);
    af[1] = loadAf(1); loadH(1, hA[1], hB[1]);

    #pragma unroll
    for (int j = 0; j < NSUBS; ++j) {
        const int cur = j & 1;

        const f32x16 kZ = {};
        f32x16 sc = __builtin_amdgcn_mfma_f32_32x32x16_bf16(af[cur], Bgh.v, kZ, 0, 0, 0);
        sc = __builtin_amdgcn_mfma_f32_32x32x16_bf16(af[cur], Bgl.v, sc, 0, 0, 0);

        if (j + 2 < NSUBS) af[cur] = loadAf(j + 2);

        unsigned a[8];
        #pragma unroll
        for (int p = 0; p < 8; ++p) {
            const float e0 = __builtin_amdgcn_exp2f(sc[2*p]);
            const float e1 = __builtin_amdgcn_exp2f(sc[2*p+1]);
            lsA += e0; lsB += e1;
            __hip_bfloat162 h2 = __float22bfloat162_rn(make_float2(e0, e1));
            a[p] = *(unsigned*)&h2;
        }
        const auto s02 = __builtin_amdgcn_permlane32_swap(a[0], a[2], false, false);
        const auto s13 = __builtin_amdgcn_permlane32_swap(a[1], a[3], false, false);
        const auto s46 = __builtin_amdgcn_permlane32_swap(a[4], a[6], false, false);
        const auto s57 = __builtin_amdgcn_permlane32_swap(a[5], a[7], false, false);

        U4 P0, P1;
        P0.u[0] = s02[0]; P0.u[1] = s13[0]; P0.u[2] = s02[1]; P0.u[3] = s13[1];
        P1.u[0] = s46[0]; P1.u[1] = s57[0]; P1.u[2] = s46[1]; P1.u[3] = s57[1];

        union U2x { short8 v; uint4 q; } Ax;
        __builtin_amdgcn_s_setprio(1);
        Ax.q = hA[cur][0];
        acc0 = __builtin_amdgcn_mfma_f32_32x32x16_bf16(Ax.v, P0.v, acc0, 0, 0, 0);
        Ax.q = hB[cur][0];
        acc1 = __builtin_amdgcn_mfma_f32_32x32x16_bf16(Ax.v, P0.v, acc1, 0, 0, 0);
        Ax.q = hA[cur][1];
        acc0 = __builtin_amdgcn_mfma_f32_32x32x16_bf16(Ax.v, P1.v, acc0, 0, 0, 0);
        Ax.q = hB[cur][1];
        acc1 = __builtin_amdgcn_mfma_f32_32x32x16_bf16(Ax.v, P1.v, acc1, 0, 0, 0);
        __builtin_amdgcn_s_setprio(0);

        if (j + 2 < NSUBS) loadH(j + 2, hA[cur], hB[cur]);
    }

    const float lsum = lsA + lsB;
    const float ltot = lsum + __shfl_xor(lsum, 32);

    // ---- 8-phase in-block fp32 reduction of (o, l) across the 8 waves ----
    #pragma unroll
    for (int ws = 0; ws < NSPLIT; ++ws) {
        if (w == ws) {
            if (ws == 0) {
                #pragma unroll
                for (int r = 0; r < 16; ++r) {
                    const int c0 = (r & 3) + 8 * (r >> 2) + 4 * hh;
                    s_o[c0][lm]      = acc0[r];
                    s_o[32 + c0][lm] = acc1[r];
                }
                if (hh == 0) s_l[lm] = ltot;
            } else {
                #pragma unroll
                for (int r = 0; r < 16; ++r) {
                    const int c0 = (r & 3) + 8 * (r >> 2) + 4 * hh;
                    s_o[c0][lm]      += acc0[r];
                    s_o[32 + c0][lm] += acc1[r];
                }
                if (hh == 0) s_l[lm] += ltot;
            }
        }
        __syncthreads();
    }

    // ---- epilogue: out = gamma * o / l + x (coalesced float4) ----
    {
        const float g  = gamma[0];
        const int   c  = t >> 3;            // 0..63
        const int   mg = (t & 7) * 4;       // 0,4,..,28
        const float4 ov = *(const float4*)&s_o[c][mg];
        const float4 lv = *(const float4*)&s_l[mg];
        const size_t idx = (size_t)(b * CDIM + c) * NSEQ + mt * 32 + mg;
        const float4 xv = *(const float4*)&x[idx];
        float4 r;
        r.x = g * ov.x / lv.x + xv.x;
        r.y = g * ov.y / lv.y + xv.y;
        r.z = g * ov.z / lv.z + xv.z;
        r.w = g * ov.w / lv.w + xv.w;
        *(float4*)&out[idx] = r;
    }
}

extern "C" void kernel_launch(void* const* d_in, const int* in_sizes, int n_in,
                              void* d_out, int out_size, void* d_ws, size_t ws_size,
                              hipStream_t stream) {
    const float* x     = (const float*)d_in[0];
    const float* wq    = (const float*)d_in[1];
    const float* wk    = (const float*)d_in[2];
    const float* wv    = (const float*)d_in[3];
    const float* gamma = (const float*)d_in[4];
    float* out = (float*)d_out;

    char* wsb = (char*)d_ws;
    unsigned short* f_pair = (unsigned short*)wsb;                         // 512 KB
    unsigned short* g_pair = f_pair + (size_t)BATCH * NSEQ * 16;           // 512 KB
    unsigned short* h_t    = g_pair + (size_t)BATCH * NSEQ * 16;           // 2 MB

    hipLaunchKernelGGL(prep_kernel, dim3(640), dim3(256), 0, stream,
                       x, wq, wk, wv, f_pair, g_pair, h_t);
    hipLaunchKernelGGL(attn_kernel, dim3(BATCH * 128), dim3(512), 0, stream,
                       f_pair, g_pair, h_t, x, gamma, out);
}